// Round 9
// baseline (16.289 us; speedup 1.0000x reference)
//
#include <hip/hip_runtime.h>
#include <hip/hip_bf16.h>
#include <math.h>

#define NAT 192

__device__ __forceinline__ float app_gauss(float x) {
    // reference: a = 1/(1+x/64+1e-8); a^64 via 6 squarings (rcp: ~1e-7 rel err)
    float a = __builtin_amdgcn_rcpf(1.0f + x * (1.0f / 64.0f) + 1e-8f);
    a = a * a; a = a * a; a = a * a; a = a * a; a = a * a;
    return a * a;
}

__device__ __forceinline__ float fast_tanh(float x) {
    // tanh(x) = sign(x) * (1 - 2/(e^{2|x|}+1)); v_exp_f32 is 2^x
    float ax = fabsf(x);
    float e = __builtin_amdgcn_exp2f(ax * 2.88539008177793f);  // e^{2ax}
    float t = 1.0f - 2.0f * __builtin_amdgcn_rcpf(e + 1.0f);
    return copysignf(t, x);
}

__global__ __launch_bounds__(256) void fused_kernel(
    const float* __restrict__ pos, const float* __restrict__ spec,
    const float* __restrict__ W1, const float* __restrict__ b1,
    const float* __restrict__ W2, const float* __restrict__ b2,
    const float* __restrict__ W3, const float* __restrict__ b3,
    unsigned long long* __restrict__ slots,   // packed (epoch<<32)|float_bits
    float* __restrict__ out)
{
    const int i = blockIdx.x;
    const int t = threadIdx.x;
    const int lane = t & 63, wv = t >> 6;

    __shared__ float px[NAT], py[NAT], pz[NAT], sp[NAT];
    __shared__ float cux[NAT], cuy[NAT], cuz[NAT], crr[NAT], cpw[NAT];
    __shared__ float rn6_c[NAT], w6_c[NAT];   // compacted radial list (rc=6)
    __shared__ int wave_cnt[4], wave_cnt6[4];
    __shared__ float redbuf[256];     // radial partials
    __shared__ float wavebuf[256];    // butterfly per-wave results
    __shared__ float desc_s[96];
    __shared__ float hbuf[128];
    __shared__ float h2buf[128];
    __shared__ float final4[4];

    // vectorized pos staging: 576 floats = 144 float4
    {
        const float4* p4 = (const float4*)pos;
        if (t < 144) {
            float4 v = p4[t];
            const int e0 = t * 4;
            float vals[4] = {v.x, v.y, v.z, v.w};
#pragma unroll
            for (int q = 0; q < 4; ++q) {
                int e = e0 + q, j = e / 3, c = e - j * 3;
                ((c == 0) ? px : (c == 1) ? py : pz)[j] = vals[q];
            }
        }
        if (t < NAT) sp[t] = spec[t];
    }
    __syncthreads();

    // per-call epoch token: bit pattern of pos[0] (positive float; never equals
    // the 0xAAAAAAAA poison, which has sign bit set, nor 0)
    const unsigned int K = __float_as_uint(px[0]);

    const float xi = px[i], yi = py[i], zi = pz[i];

    // ---- per-j: rnorm, radial/angular cutoff candidates ----
    float dx = 0.f, dy = 0.f, dz = 0.f, rn = 0.f, pw = 0.f, w6v = 0.f;
    bool pred4 = false, pred6 = false;
    if (t < NAT) {
        dx = xi - px[t];
        dy = yi - py[t];
        dz = zi - pz[t];
        rn = sqrtf(dx * dx + dy * dy + dz * dz + 1e-12f);
        if (rn <= 6.0f) {   // beyond rc the radial weight is exactly 0
            pred6 = true;
            // fcut: 0.5*(1+cos(pi*r/rc)) via v_cos_f32 (arg in revolutions)
            w6v = sp[t] * 0.5f * (1.0f + __builtin_amdgcn_cosf(rn * (1.0f / 12.0f)));
        }
        if (rn <= 4.0f) {   // beyond rc_ang the pair weight is exactly 0
            pred4 = true;
            pw = sp[t] * 0.5f * (1.0f + __builtin_amdgcn_cosf(rn * 0.125f));
        }
    }
    // deterministic compaction: per-wave ballot + prefix (both cutoffs)
    unsigned long long m4 = __ballot(pred4);
    unsigned long long m6 = __ballot(pred6);
    if (lane == 0) { wave_cnt[wv] = __popcll(m4); wave_cnt6[wv] = __popcll(m6); }
    __syncthreads();
    int base4 = 0, base6 = 0;
    for (int w = 0; w < wv; ++w) { base4 += wave_cnt[w]; base6 += wave_cnt6[w]; }
    if (pred4) {
        int slot = base4 + __popcll(m4 & ((1ull << lane) - 1ull));
        float inv = __builtin_amdgcn_rcpf(rn + 1e-20f);
        cux[slot] = dx * inv;
        cuy[slot] = dy * inv;
        cuz[slot] = dz * inv;
        crr[slot] = rn;
        cpw[slot] = pw;
    }
    if (pred6) {
        int slot = base6 + __popcll(m6 & ((1ull << lane) - 1ull));
        rn6_c[slot] = rn;
        w6_c[slot] = w6v;
    }
    const int nn = wave_cnt[0] + wave_cnt[1] + wave_cnt[2] + wave_cnt[3];
    const int n6 = wave_cnt6[0] + wave_cnt6[1] + wave_cnt6[2] + wave_cnt6[3];
    __syncthreads();

    // ---- radial: thread = (s 0..31, g 0..7), strided over compacted list ----
    {
        const int s = t & 31, g = t >> 5;
        const float Rs = 0.25f + (float)s * 0.1796875f;  // (6-0.25)/32
        float acc = 0.0f;
        for (int j = g; j < n6; j += 8) {
            float d = rn6_c[j] - Rs;
            acc += w6_c[j] * app_gauss(0.5f * d * d);
        }
        redbuf[s * 8 + g] = acc;
    }

    // ---- angular: upper-triangle pair loop (j<->k symmetric, x2 weight) ----
    const float CT[8] = {1.0f, 0.92387953f, 0.70710678f, 0.38268343f,
                         -4.37113883e-08f, -0.38268343f, -0.70710678f, -0.92387953f};
    const float ST[8] = {0.0f, 0.38268343f, 0.70710678f, 0.92387953f,
                         1.0f, 0.92387953f, 0.70710678f, 0.38268343f};

    float av[64];
#pragma unroll
    for (int v = 0; v < 64; ++v) av[v] = 0.0f;

    const int T = (nn * (nn + 1)) >> 1;
    const float fn2 = 2.0f * (float)nn + 1.0f;
    for (int p = t; p < T; p += 256) {
        // decode triangle index -> (a,b), a<=b
        int a = (int)((fn2 - sqrtf(fn2 * fn2 - 8.0f * (float)p)) * 0.5f);
        if (a < 0) a = 0;
        int rs = a * nn - ((a * (a - 1)) >> 1);
        while (rs > p) { --a; rs = a * nn - ((a * (a - 1)) >> 1); }
        int rsn = (a + 1) * nn - (((a + 1) * a) >> 1);
        while (p >= rsn) { ++a; rs = rsn; rsn = (a + 1) * nn - (((a + 1) * a) >> 1); }
        int b = a + (p - rs);

        float c = cux[a] * cux[b] + cuy[a] * cuy[b] + cuz[a] * cuz[b];
        float s2 = 1.0f - c * c;
        s2 = s2 < 0.0f ? 0.0f : s2;
        float sT = sqrtf(s2 + 1e-6f);
        float P = cpw[a] * cpw[b] * ((a == b) ? 1.0f : 2.0f);
        float rr = 0.5f * (crr[a] + crr[b]);
        float angv[8];
#pragma unroll
        for (int tt = 0; tt < 8; ++tt) {
            float bse = 0.5f * (1.0f + c * CT[tt] + sT * ST[tt]);
            float b2v = bse * bse;
            float b4v = b2v * b2v;
            angv[tt] = b4v * b4v;  // ^zeta=8
        }
#pragma unroll
        for (int ss = 0; ss < 8; ++ss) {
            float d = rr - (0.25f + (float)ss * 0.46875f);  // (4-0.25)/8
            float rg = app_gauss(0.5f * d * d) * P;
#pragma unroll
            for (int tt = 0; tt < 8; ++tt)
                av[ss * 8 + tt] += rg * angv[tt];
        }
    }

    // ---- multi-value butterfly: lane l ends with total of value l ----
#define STAGE(h)                                                         \
    {                                                                    \
        const bool up = (lane & h) != 0;                                 \
        _Pragma("unroll")                                                \
        for (int k = 0; k < h; ++k) {                                    \
            float mine   = up ? av[k + h] : av[k];                       \
            float theirs = up ? av[k] : av[k + h];                       \
            av[k] = mine + __shfl_xor(theirs, h, 64);                    \
        }                                                                \
    }
    STAGE(32) STAGE(16) STAGE(8) STAGE(4) STAGE(2) STAGE(1)
#undef STAGE
    wavebuf[wv * 64 + lane] = av[0];
    __syncthreads();

    if (t < 32) {
        float r = 0.0f;
#pragma unroll
        for (int g = 0; g < 8; ++g) r += redbuf[t * 8 + g];
        desc_s[t] = r;
    }
    if (t < 64)
        desc_s[32 + t] = wavebuf[t] + wavebuf[64 + t] + wavebuf[128 + t] + wavebuf[192 + t];
    __syncthreads();

    // ---- MLP: 2 SAME-WAVE lanes per neuron (combine via shfl_xor(1)) ----
    const int n = t >> 1, h = t & 1;
    {
        float a1 = (h == 0) ? b1[n] : 0.0f;
        const int f0 = h * 48;
        for (int f = f0; f < f0 + 48; ++f) a1 += desc_s[f] * W1[f * 128 + n];
        float tot = a1 + __shfl_xor(a1, 1, 64);
        if (h == 0) hbuf[n] = fast_tanh(tot);
    }
    __syncthreads();
    {
        float a2 = (h == 0) ? b2[n] : 0.0f;
        const int f0 = h * 64;
        for (int f = f0; f < f0 + 64; ++f) a2 += hbuf[f] * W2[f * 128 + n];
        float tot = a2 + __shfl_xor(a2, 1, 64);
        if (h == 0) h2buf[n] = fast_tanh(tot) * W3[n];
    }
    __syncthreads();

    if (t < 64) {
        float v = h2buf[t] + h2buf[t + 64];
#pragma unroll
        for (int o = 32; o > 0; o >>= 1) v += __shfl_xor(v, o, 64);
        if (t == 0) {
            // single 64-bit publish: hi = epoch token, lo = energy bits.
            // Tag and value share one atomic word -> RELAXED is sufficient.
            unsigned long long pk =
                ((unsigned long long)K << 32) |
                (unsigned long long)__float_as_uint(v + b3[0]);
            __hip_atomic_store(&slots[i], pk, __ATOMIC_RELAXED,
                               __HIP_MEMORY_SCOPE_AGENT);
        }
    }

    // ---- block 0: spin until every slot carries this call's token ----
    if (i == 0) {
        float v = 0.0f;
        if (t < NAT) {
            unsigned long long pk;
            int guard = 0;
            do {
                pk = __hip_atomic_load(&slots[t], __ATOMIC_RELAXED,
                                       __HIP_MEMORY_SCOPE_AGENT);
                if (++guard > 10000000) break;   // fail-safe against hang
            } while ((unsigned int)(pk >> 32) != K);
            v = __uint_as_float((unsigned int)pk);
        }
#pragma unroll
        for (int o = 32; o > 0; o >>= 1) v += __shfl_xor(v, o, 64);
        if (lane == 0) final4[wv] = v;
        __syncthreads();
        if (t == 0) out[0] = final4[0] + final4[1] + final4[2] + final4[3];
        // reset slots for the next call (hi=0 != K always)
        if (t < NAT)
            __hip_atomic_store(&slots[t], 0ull, __ATOMIC_RELAXED,
                               __HIP_MEMORY_SCOPE_AGENT);
    }
}

extern "C" void kernel_launch(void* const* d_in, const int* in_sizes, int n_in,
                              void* d_out, int out_size, void* d_ws, size_t ws_size,
                              hipStream_t stream) {
    const float* pos  = (const float*)d_in[0];
    const float* spec = (const float*)d_in[1];
    const float* W1   = (const float*)d_in[2];
    const float* b1   = (const float*)d_in[3];
    const float* W2   = (const float*)d_in[4];
    const float* b2   = (const float*)d_in[5];
    const float* W3   = (const float*)d_in[6];
    const float* b3   = (const float*)d_in[7];

    unsigned long long* slots = (unsigned long long*)d_ws;  // 192 packed slots

    fused_kernel<<<NAT, 256, 0, stream>>>(pos, spec, W1, b1, W2, b2, W3, b3,
                                          slots, (float*)d_out);
}

// Round 10
// 14.959 us; speedup vs baseline: 1.0889x; 1.0889x over previous
//
#include <hip/hip_runtime.h>
#include <hip/hip_bf16.h>
#include <math.h>

#define NAT 192

__device__ __forceinline__ float app_gauss(float x) {
    // reference: a = 1/(1+x/64+1e-8); a^64 via 6 squarings (rcp: ~1e-7 rel err)
    float a = __builtin_amdgcn_rcpf(1.0f + x * (1.0f / 64.0f) + 1e-8f);
    a = a * a; a = a * a; a = a * a; a = a * a; a = a * a;
    return a * a;
}

__device__ __forceinline__ float fast_tanh(float x) {
    // tanh(x) = sign(x) * (1 - 2/(e^{2|x|}+1)); v_exp_f32 is 2^x
    float ax = fabsf(x);
    float e = __builtin_amdgcn_exp2f(ax * 2.88539008177793f);  // e^{2ax}
    float t = 1.0f - 2.0f * __builtin_amdgcn_rcpf(e + 1.0f);
    return copysignf(t, x);
}

__global__ __launch_bounds__(256) void fused_kernel(
    const float* __restrict__ pos, const float* __restrict__ spec,
    const float* __restrict__ W1, const float* __restrict__ b1,
    const float* __restrict__ W2, const float* __restrict__ b2,
    const float* __restrict__ W3, const float* __restrict__ b3,
    unsigned long long* __restrict__ slots,   // packed (epoch<<32)|float_bits
    float* __restrict__ out)
{
    const int i = blockIdx.x;
    const int t = threadIdx.x;
    const int lane = t & 63, wv = t >> 6;

    __shared__ float px[NAT], py[NAT], pz[NAT], sp[NAT];
    __shared__ float rn_s[NAT], w6[NAT];
    __shared__ float cux[NAT], cuy[NAT], cuz[NAT], crr[NAT], cpw[NAT];
    __shared__ int wave_cnt[4];
    __shared__ float redbuf[256];     // radial partials
    __shared__ float wavebuf[256];    // butterfly per-wave results
    __shared__ float desc_s[96];
    __shared__ float part[2][128];
    __shared__ float hbuf[128];
    __shared__ float h2buf[128];
    __shared__ float final4[4];

    // vectorized pos staging: 576 floats = 144 float4
    {
        const float4* p4 = (const float4*)pos;
        if (t < 144) {
            float4 v = p4[t];
            const int e0 = t * 4;
            float vals[4] = {v.x, v.y, v.z, v.w};
#pragma unroll
            for (int q = 0; q < 4; ++q) {
                int e = e0 + q, j = e / 3, c = e - j * 3;
                ((c == 0) ? px : (c == 1) ? py : pz)[j] = vals[q];
            }
        }
        if (t < NAT) sp[t] = spec[t];
    }
    __syncthreads();

    // per-call epoch token: bit pattern of pos[0] (positive float; never equals
    // the 0xAAAAAAAA poison, which has sign bit set, nor 0)
    const unsigned int K = __float_as_uint(px[0]);

    const float xi = px[i], yi = py[i], zi = pz[i];

    // ---- per-j: rnorm, radial weight, angular-cutoff candidates ----
    float dx = 0.f, dy = 0.f, dz = 0.f, rn = 0.f, pw = 0.f;
    bool pred = false;
    if (t < NAT) {
        dx = xi - px[t];
        dy = yi - py[t];
        dz = zi - pz[t];
        rn = sqrtf(dx * dx + dy * dy + dz * dz + 1e-12f);
        rn_s[t] = rn;
        // fcut: 0.5*(1+cos(pi*r/rc)) via v_cos_f32 (arg in revolutions)
        float f6 = (rn <= 6.0f)
                       ? 0.5f * (1.0f + __builtin_amdgcn_cosf(rn * (1.0f / 12.0f)))
                       : 0.0f;
        w6[t] = sp[t] * f6;
        if (rn <= 4.0f) {   // beyond rc_ang pair weight is exactly 0
            pred = true;
            float f4 = 0.5f * (1.0f + __builtin_amdgcn_cosf(rn * 0.125f));
            pw = sp[t] * f4;
        }
    }
    // deterministic compaction: per-wave ballot + prefix
    unsigned long long m = __ballot(pred);
    if (lane == 0) wave_cnt[wv] = __popcll(m);
    __syncthreads();
    int base = 0;
    for (int w = 0; w < wv; ++w) base += wave_cnt[w];
    if (pred) {
        int slot = base + __popcll(m & ((1ull << lane) - 1ull));
        float inv = __builtin_amdgcn_rcpf(rn + 1e-20f);
        cux[slot] = dx * inv;
        cuy[slot] = dy * inv;
        cuz[slot] = dz * inv;
        crr[slot] = rn;
        cpw[slot] = pw;
    }
    const int nn = wave_cnt[0] + wave_cnt[1] + wave_cnt[2] + wave_cnt[3];
    __syncthreads();

    // ---- radial: thread = (s 0..31, g 0..7), strided over j ----
    {
        const int s = t & 31, g = t >> 5;
        const float Rs = 0.25f + (float)s * 0.1796875f;  // (6-0.25)/32
        float acc = 0.0f;
        for (int j = g; j < NAT; j += 8) {
            float d = rn_s[j] - Rs;
            acc += w6[j] * app_gauss(0.5f * d * d);
        }
        redbuf[s * 8 + g] = acc;
    }

    // ---- angular: upper-triangle pair loop (j<->k symmetric, x2 weight) ----
    const float CT[8] = {1.0f, 0.92387953f, 0.70710678f, 0.38268343f,
                         -4.37113883e-08f, -0.38268343f, -0.70710678f, -0.92387953f};
    const float ST[8] = {0.0f, 0.38268343f, 0.70710678f, 0.92387953f,
                         1.0f, 0.92387953f, 0.70710678f, 0.38268343f};

    float av[64];
#pragma unroll
    for (int v = 0; v < 64; ++v) av[v] = 0.0f;

    const int T = (nn * (nn + 1)) >> 1;
    const float fn2 = 2.0f * (float)nn + 1.0f;
    for (int p = t; p < T; p += 256) {
        // decode triangle index -> (a,b), a<=b
        int a = (int)((fn2 - sqrtf(fn2 * fn2 - 8.0f * (float)p)) * 0.5f);
        if (a < 0) a = 0;
        int rs = a * nn - ((a * (a - 1)) >> 1);
        while (rs > p) { --a; rs = a * nn - ((a * (a - 1)) >> 1); }
        int rsn = (a + 1) * nn - (((a + 1) * a) >> 1);
        while (p >= rsn) { ++a; rs = rsn; rsn = (a + 1) * nn - (((a + 1) * a) >> 1); }
        int b = a + (p - rs);

        float c = cux[a] * cux[b] + cuy[a] * cuy[b] + cuz[a] * cuz[b];
        float s2 = 1.0f - c * c;
        s2 = s2 < 0.0f ? 0.0f : s2;
        float sT = sqrtf(s2 + 1e-6f);
        float P = cpw[a] * cpw[b] * ((a == b) ? 1.0f : 2.0f);
        float rr = 0.5f * (crr[a] + crr[b]);
        float angv[8];
#pragma unroll
        for (int tt = 0; tt < 8; ++tt) {
            float bse = 0.5f * (1.0f + c * CT[tt] + sT * ST[tt]);
            float b2v = bse * bse;
            float b4v = b2v * b2v;
            angv[tt] = b4v * b4v;  // ^zeta=8
        }
#pragma unroll
        for (int ss = 0; ss < 8; ++ss) {
            float d = rr - (0.25f + (float)ss * 0.46875f);  // (4-0.25)/8
            float rg = app_gauss(0.5f * d * d) * P;
#pragma unroll
            for (int tt = 0; tt < 8; ++tt)
                av[ss * 8 + tt] += rg * angv[tt];
        }
    }

    // ---- multi-value butterfly: lane l ends with total of value l ----
#define STAGE(h)                                                         \
    {                                                                    \
        const bool up = (lane & h) != 0;                                 \
        _Pragma("unroll")                                                \
        for (int k = 0; k < h; ++k) {                                    \
            float mine   = up ? av[k + h] : av[k];                       \
            float theirs = up ? av[k] : av[k + h];                       \
            av[k] = mine + __shfl_xor(theirs, h, 64);                    \
        }                                                                \
    }
    STAGE(32) STAGE(16) STAGE(8) STAGE(4) STAGE(2) STAGE(1)
#undef STAGE
    wavebuf[wv * 64 + lane] = av[0];
    __syncthreads();

    if (t < 32) {
        float r = 0.0f;
#pragma unroll
        for (int g = 0; g < 8; ++g) r += redbuf[t * 8 + g];
        desc_s[t] = r;
    }
    if (t < 64)
        desc_s[32 + t] = wavebuf[t] + wavebuf[64 + t] + wavebuf[128 + t] + wavebuf[192 + t];
    __syncthreads();

    // ---- MLP: 2 threads per neuron, weights from L2 (broadcast-hot) ----
    const int nidx = t & 127, hh = t >> 7;
    {
        float a1 = (hh == 0) ? b1[nidx] : 0.0f;
        const int f0 = hh * 48;
        for (int f = f0; f < f0 + 48; ++f) a1 += desc_s[f] * W1[f * 128 + nidx];
        part[hh][nidx] = a1;
    }
    __syncthreads();
    if (t < 128) hbuf[t] = fast_tanh(part[0][t] + part[1][t]);
    __syncthreads();
    {
        float a2 = (hh == 0) ? b2[nidx] : 0.0f;
        const int f0 = hh * 64;
        for (int f = f0; f < f0 + 64; ++f) a2 += hbuf[f] * W2[f * 128 + nidx];
        part[hh][nidx] = a2;
    }
    __syncthreads();
    if (t < 128) h2buf[t] = fast_tanh(part[0][t] + part[1][t]) * W3[t];
    __syncthreads();

    if (t < 64) {
        float v = h2buf[t] + h2buf[t + 64];
#pragma unroll
        for (int o = 32; o > 0; o >>= 1) v += __shfl_xor(v, o, 64);
        if (t == 0) {
            // single 64-bit publish: hi = epoch token, lo = energy bits.
            // Tag and value share one atomic word -> RELAXED is sufficient.
            unsigned long long pk =
                ((unsigned long long)K << 32) |
                (unsigned long long)__float_as_uint(v + b3[0]);
            __hip_atomic_store(&slots[i], pk, __ATOMIC_RELAXED,
                               __HIP_MEMORY_SCOPE_AGENT);
        }
    }

    // ---- block 0: spin until every slot carries this call's token ----
    if (i == 0) {
        float v = 0.0f;
        if (t < NAT) {
            unsigned long long pk;
            int guard = 0;
            do {
                pk = __hip_atomic_load(&slots[t], __ATOMIC_RELAXED,
                                       __HIP_MEMORY_SCOPE_AGENT);
                if (++guard > 10000000) break;   // fail-safe against hang
            } while ((unsigned int)(pk >> 32) != K);
            v = __uint_as_float((unsigned int)pk);
        }
#pragma unroll
        for (int o = 32; o > 0; o >>= 1) v += __shfl_xor(v, o, 64);
        if (lane == 0) final4[wv] = v;
        __syncthreads();
        if (t == 0) out[0] = final4[0] + final4[1] + final4[2] + final4[3];
        // reset slots for the next call (hi=0 != K always)
        if (t < NAT)
            __hip_atomic_store(&slots[t], 0ull, __ATOMIC_RELAXED,
                               __HIP_MEMORY_SCOPE_AGENT);
    }
}

extern "C" void kernel_launch(void* const* d_in, const int* in_sizes, int n_in,
                              void* d_out, int out_size, void* d_ws, size_t ws_size,
                              hipStream_t stream) {
    const float* pos  = (const float*)d_in[0];
    const float* spec = (const float*)d_in[1];
    const float* W1   = (const float*)d_in[2];
    const float* b1   = (const float*)d_in[3];
    const float* W2   = (const float*)d_in[4];
    const float* b2   = (const float*)d_in[5];
    const float* W3   = (const float*)d_in[6];
    const float* b3   = (const float*)d_in[7];

    unsigned long long* slots = (unsigned long long*)d_ws;  // 192 packed slots

    fused_kernel<<<NAT, 256, 0, stream>>>(pos, spec, W1, b1, W2, b2, W3, b3,
                                          slots, (float*)d_out);
}